// Round 3
// baseline (287.408 us; speedup 1.0000x reference)
//
#include <hip/hip_runtime.h>
#include <hip/hip_bf16.h>

typedef __bf16 bf16_t;
typedef __bf16 bf16x8 __attribute__((ext_vector_type(8)));
typedef float  f32x4  __attribute__((ext_vector_type(4)));

#define TPW   8                      // 16-row tiles per wave
#define WAVES 4
#define ROWS_PER_BLOCK (WAVES * TPW * 16)   // 512
#define HSTRIDE 65                   // 64 + 1 pad (f32)
#define CSTRIDE 33                   // 32 + 1 pad (f32)

// load 8 consecutive fp32 input elements (16B-aligned offset) as a bf16 fragment
__device__ __forceinline__ bf16x8 ldrow8(const float* base, size_t elem_off) {
    const float* p = base + elem_off;
    f32x4 a = *(const f32x4*)p;
    f32x4 b = *(const f32x4*)(p + 4);
    bf16x8 r;
    #pragma unroll
    for (int j = 0; j < 4; ++j) { r[j] = (bf16_t)a[j]; r[j+4] = (bf16_t)b[j]; }
    return r;
}

__global__ __launch_bounds__(256) void nerf_fused(
    const float* __restrict__ pos, const float* __restrict__ dir,
    const float* __restrict__ W1, const float* __restrict__ b1,
    const float* __restrict__ W2, const float* __restrict__ b2,
    const float* __restrict__ W3, const float* __restrict__ b3,
    const float* __restrict__ W4, const float* __restrict__ b4,
    const float* __restrict__ W5, const float* __restrict__ b5,
    float* __restrict__ outD, float* __restrict__ outC)
{
    __shared__ float hbuf[WAVES][16 * HSTRIDE];
    __shared__ float cbuf[WAVES][16 * CSTRIDE];

    const int tid  = threadIdx.x;
    const int w    = tid >> 6;
    const int lane = tid & 63;
    const int q    = lane >> 4;    // quad 0..3
    const int n    = lane & 15;    // col / row-within-tile

    float* hb = hbuf[w];
    float* cb = cbuf[w];

    // ---------------- weight fragments (B-operand layout) ----------------
    // B[k = 8*q + j][col = n]; K=32 per fragment.
    bf16x8 w1f[4], w2f[2], w3f[4], w4f[2][4], w5f[2];
    #pragma unroll
    for (int t = 0; t < 4; ++t)
        #pragma unroll
        for (int j = 0; j < 8; ++j)
            w1f[t][j] = (bf16_t)W1[(8*q + j) * 64 + 16*t + n];          // [32,64]
    #pragma unroll
    for (int kt = 0; kt < 2; ++kt)
        #pragma unroll
        for (int j = 0; j < 8; ++j)
            w2f[kt][j] = (bf16_t)W2[(32*kt + 8*q + j) * 16 + n];        // [64,16]
    #pragma unroll
    for (int t = 0; t < 4; ++t)
        #pragma unroll
        for (int j = 0; j < 8; ++j)
            w3f[t][j] = (bf16_t)W3[(8*q + j) * 64 + 16*t + n];          // [32,64]
    #pragma unroll
    for (int kt = 0; kt < 2; ++kt)
        #pragma unroll
        for (int t = 0; t < 4; ++t)
            #pragma unroll
            for (int j = 0; j < 8; ++j)
                w4f[kt][t][j] = (bf16_t)W4[(32*kt + 8*q + j) * 64 + 16*t + n];  // [64,64]
    #pragma unroll
    for (int kt = 0; kt < 2; ++kt)
        #pragma unroll
        for (int j = 0; j < 8; ++j)
            w5f[kt][j] = (n < 3) ? (bf16_t)W5[(32*kt + 8*q + j) * 3 + n]
                                 : (bf16_t)0.0f;                         // [64,3] padded
    float b1f[4], b3f[4], b4f[4];
    #pragma unroll
    for (int t = 0; t < 4; ++t) {
        b1f[t] = b1[16*t + n];
        b3f[t] = b3[16*t + n];
        b4f[t] = b4[16*t + n];
    }
    const float b2f = b2[n];
    const float b5f = (n < 3) ? b5[n] : 0.0f;

    const f32x4 zero4 = {0.f, 0.f, 0.f, 0.f};

    const int waveRow0 = blockIdx.x * ROWS_PER_BLOCK + w * (TPW * 16);

    // software-prefetched position A-fragment: A[m=n][k=8q+j]
    bf16x8 pfrag = ldrow8(pos, (size_t)(waveRow0 + n) * 32 + 8*q);

    for (int t = 0; t < TPW; ++t) {
        const int row0 = waveRow0 + t * 16;
        const int tn   = (t + 1 < TPW) ? t + 1 : t;
        bf16x8 pnext = ldrow8(pos, (size_t)(waveRow0 + tn*16 + n) * 32 + 8*q);

        const size_t db = (size_t)(row0 + n) * 3;
        const float dx = dir[db + 0];
        const float dy = dir[db + 1];
        const float dz = dir[db + 2];

        // ---- L1: H = relu(X @ W1 + b1)  [16x64] ----
        f32x4 acc1[4];
        #pragma unroll
        for (int tt = 0; tt < 4; ++tt)
            acc1[tt] = __builtin_amdgcn_mfma_f32_16x16x32_bf16(pfrag, w1f[tt], zero4, 0, 0, 0);
        #pragma unroll
        for (int tt = 0; tt < 4; ++tt)
            #pragma unroll
            for (int r = 0; r < 4; ++r)
                hb[(4*q + r) * HSTRIDE + 16*tt + n] = fmaxf(acc1[tt][r] + b1f[tt], 0.f);
        __syncthreads();
        bf16x8 a2[2];
        #pragma unroll
        for (int kt = 0; kt < 2; ++kt)
            #pragma unroll
            for (int j = 0; j < 8; ++j)
                a2[kt][j] = (bf16_t)hb[n * HSTRIDE + 32*kt + 8*q + j];

        // ---- L2: density = H @ W2 + b2  [16x16] (no relu) ----
        f32x4 acc2 = __builtin_amdgcn_mfma_f32_16x16x32_bf16(a2[0], w2f[0], zero4, 0, 0, 0);
        acc2 = __builtin_amdgcn_mfma_f32_16x16x32_bf16(a2[1], w2f[1], acc2, 0, 0, 0);
        #pragma unroll
        for (int r = 0; r < 4; ++r)
            cb[(4*q + r) * CSTRIDE + n] = acc2[r] + b2f;

        // ---- SH(dir) -> concat cols 16..31 ----
        {
            const float xx = dx*dx, yy = dy*dy, zz = dz*dz;
            float c0, c1, c2, c3;
            if (q == 0) {
                c0 = 0.28209479177387814f;
                c1 = 0.4886025119029199f * dy;
                c2 = 0.4886025119029199f * dz;
                c3 = 0.4886025119029199f * dx;
            } else if (q == 1) {
                c0 = 1.0925484305920792f * dx * dy;
                c1 = 1.0925484305920792f * dy * dz;
                c2 = 0.9461746957575601f * zz - 0.31539156525252f;
                c3 = 1.0925484305920792f * dx * dz;
            } else if (q == 2) {
                c0 = 0.5462742152960396f * (xx - yy);
                c1 = 0.5900435899266435f * dy * (3.f*xx - yy);
                c2 = 2.890611442640554f * dx * dy * dz;
                c3 = 0.4570457994644658f * dy * (5.f*zz - 1.f);
            } else {
                c0 = 0.3731763325901154f * dz * (5.f*zz - 3.f);
                c1 = 0.4570457994644658f * dx * (5.f*zz - 1.f);
                c2 = 1.445305721320277f  * dz * (xx - yy);
                c3 = 0.5900435899266435f * dx * (xx - 3.f*yy);
            }
            float* p = cb + n * CSTRIDE + 16 + 4*q;
            p[0] = c0; p[1] = c1; p[2] = c2; p[3] = c3;
        }
        __syncthreads();

        // ---- density store, fp32, coalesced f32x4 via LDS readback ----
        {
            const int rr = lane >> 2;            // 0..15
            const int cg = lane & 3;             // 4-col group
            const float* src = cb + rr * CSTRIDE + 4*cg;
            f32x4 dv = { src[0], src[1], src[2], src[3] };
            *(f32x4*)(outD + (size_t)(row0 + rr) * 16 + 4*cg) = dv;
        }

        // ---- L3: relu(concat @ W3 + b3)  [16x64] ----
        bf16x8 a3;
        #pragma unroll
        for (int j = 0; j < 8; ++j)
            a3[j] = (bf16_t)cb[n * CSTRIDE + 8*q + j];
        f32x4 acc3[4];
        #pragma unroll
        for (int tt = 0; tt < 4; ++tt)
            acc3[tt] = __builtin_amdgcn_mfma_f32_16x16x32_bf16(a3, w3f[tt], zero4, 0, 0, 0);
        __syncthreads();   // a2 reads of hb done in all waves; safe to overwrite
        #pragma unroll
        for (int tt = 0; tt < 4; ++tt)
            #pragma unroll
            for (int r = 0; r < 4; ++r)
                hb[(4*q + r) * HSTRIDE + 16*tt + n] = fmaxf(acc3[tt][r] + b3f[tt], 0.f);
        __syncthreads();
        bf16x8 a4[2];
        #pragma unroll
        for (int kt = 0; kt < 2; ++kt)
            #pragma unroll
            for (int j = 0; j < 8; ++j)
                a4[kt][j] = (bf16_t)hb[n * HSTRIDE + 32*kt + 8*q + j];

        // ---- L4: relu(H3 @ W4 + b4)  [16x64] ----
        f32x4 acc4[4];
        #pragma unroll
        for (int tt = 0; tt < 4; ++tt) {
            acc4[tt] = __builtin_amdgcn_mfma_f32_16x16x32_bf16(a4[0], w4f[0][tt], zero4, 0, 0, 0);
            acc4[tt] = __builtin_amdgcn_mfma_f32_16x16x32_bf16(a4[1], w4f[1][tt], acc4[tt], 0, 0, 0);
        }
        __syncthreads();
        #pragma unroll
        for (int tt = 0; tt < 4; ++tt)
            #pragma unroll
            for (int r = 0; r < 4; ++r)
                hb[(4*q + r) * HSTRIDE + 16*tt + n] = fmaxf(acc4[tt][r] + b4f[tt], 0.f);
        __syncthreads();
        bf16x8 a5[2];
        #pragma unroll
        for (int kt = 0; kt < 2; ++kt)
            #pragma unroll
            for (int j = 0; j < 8; ++j)
                a5[kt][j] = (bf16_t)hb[n * HSTRIDE + 32*kt + 8*q + j];

        // ---- L5: color = sigmoid(H4 @ W5 + b5)  [16x3], fp32 store ----
        f32x4 acc5 = __builtin_amdgcn_mfma_f32_16x16x32_bf16(a5[0], w5f[0], zero4, 0, 0, 0);
        acc5 = __builtin_amdgcn_mfma_f32_16x16x32_bf16(a5[1], w5f[1], acc5, 0, 0, 0);
        if (n < 3) {
            #pragma unroll
            for (int r = 0; r < 4; ++r) {
                float v = acc5[r] + b5f;
                outC[(size_t)(row0 + 4*q + r) * 3 + n] = 1.f / (1.f + __expf(-v));
            }
        }
        __syncthreads();   // WAR guard before next iteration overwrites hb/cb

        pfrag = pnext;
    }
}

extern "C" void kernel_launch(void* const* d_in, const int* in_sizes, int n_in,
                              void* d_out, int out_size, void* d_ws, size_t ws_size,
                              hipStream_t stream) {
    const float* pos = (const float*)d_in[0];
    const float* dir = (const float*)d_in[1];
    const float* W1  = (const float*)d_in[2];
    const float* b1  = (const float*)d_in[3];
    const float* W2  = (const float*)d_in[4];
    const float* b2  = (const float*)d_in[5];
    const float* W3  = (const float*)d_in[6];
    const float* b3  = (const float*)d_in[7];
    const float* W4  = (const float*)d_in[8];
    const float* b4  = (const float*)d_in[9];
    const float* W5  = (const float*)d_in[10];
    const float* b5  = (const float*)d_in[11];

    const int N = in_sizes[0] / 32;           // 1<<20
    float* outD = (float*)d_out;              // [N,16]
    float* outC = outD + (size_t)N * 16;      // [N,3]

    const int grid = N / ROWS_PER_BLOCK;      // 2048
    nerf_fused<<<grid, WAVES * 64, 0, stream>>>(pos, dir, W1, b1, W2, b2, W3, b3,
                                                W4, b4, W5, b5, outD, outC);
}

// Round 4
// 283.654 us; speedup vs baseline: 1.0132x; 1.0132x over previous
//
#include <hip/hip_runtime.h>
#include <hip/hip_bf16.h>

typedef __bf16 bf16_t;
typedef __bf16 bf16x8 __attribute__((ext_vector_type(8)));
typedef float  f32x4  __attribute__((ext_vector_type(4)));

#define TPW   8                      // 16-row tiles per wave
#define WAVES 4
#define ROWS_PER_BLOCK (WAVES * TPW * 16)   // 512
// Strides chosen so ds_read_b128 is 16B-aligned (mult of 4 f32) and the
// per-lane start banks cover all eight 4-bank windows evenly (4*odd).
#define HS 68                        // hb row stride (f32)
#define CS 36                        // cb row stride (f32)

// compiler-level ordering fence for the wave-synchronous LDS exchanges
// (DS ops execute in order within a wave; no cross-wave sharing exists).
#define FENCE() __asm__ volatile("" ::: "memory")

// load 8 consecutive fp32 (16B-aligned) as a bf16 fragment
__device__ __forceinline__ bf16x8 ldrow8(const float* base, size_t elem_off) {
    const float* p = base + elem_off;
    f32x4 a = *(const f32x4*)p;
    f32x4 b = *(const f32x4*)(p + 4);
    bf16x8 r;
    #pragma unroll
    for (int j = 0; j < 4; ++j) { r[j] = (bf16_t)a[j]; r[j+4] = (bf16_t)b[j]; }
    return r;
}

__global__ __launch_bounds__(256) void nerf_fused(
    const float* __restrict__ pos, const float* __restrict__ dir,
    const float* __restrict__ W1, const float* __restrict__ b1,
    const float* __restrict__ W2, const float* __restrict__ b2,
    const float* __restrict__ W3, const float* __restrict__ b3,
    const float* __restrict__ W4, const float* __restrict__ b4,
    const float* __restrict__ W5, const float* __restrict__ b5,
    float* __restrict__ outD, float* __restrict__ outC)
{
    __shared__ float hbuf[WAVES][16 * HS];
    __shared__ float cbuf[WAVES][16 * CS];

    const int tid  = threadIdx.x;
    const int w    = tid >> 6;
    const int lane = tid & 63;
    const int q    = lane >> 4;    // quad 0..3
    const int n    = lane & 15;    // col / row-within-tile

    float* hb = hbuf[w];
    float* cb = cbuf[w];

    // ---------------- weight fragments (B-operand layout) ----------------
    // B[k = 8*q + j][col = n]; K=32 per fragment. (verified layouts, unchanged)
    bf16x8 w1f[4], w2f[2], w3f[4], w4f[2][4], w5f[2];
    #pragma unroll
    for (int t = 0; t < 4; ++t)
        #pragma unroll
        for (int j = 0; j < 8; ++j)
            w1f[t][j] = (bf16_t)W1[(8*q + j) * 64 + 16*t + n];          // [32,64]
    #pragma unroll
    for (int kt = 0; kt < 2; ++kt)
        #pragma unroll
        for (int j = 0; j < 8; ++j)
            w2f[kt][j] = (bf16_t)W2[(32*kt + 8*q + j) * 16 + n];        // [64,16]
    #pragma unroll
    for (int t = 0; t < 4; ++t)
        #pragma unroll
        for (int j = 0; j < 8; ++j)
            w3f[t][j] = (bf16_t)W3[(8*q + j) * 64 + 16*t + n];          // [32,64]
    #pragma unroll
    for (int kt = 0; kt < 2; ++kt)
        #pragma unroll
        for (int t = 0; t < 4; ++t)
            #pragma unroll
            for (int j = 0; j < 8; ++j)
                w4f[kt][t][j] = (bf16_t)W4[(32*kt + 8*q + j) * 64 + 16*t + n];  // [64,64]
    #pragma unroll
    for (int kt = 0; kt < 2; ++kt)
        #pragma unroll
        for (int j = 0; j < 8; ++j)
            w5f[kt][j] = (n < 3) ? (bf16_t)W5[(32*kt + 8*q + j) * 3 + n]
                                 : (bf16_t)0.0f;                         // [64,3] padded
    float b1f[4], b3f[4], b4f[4];
    #pragma unroll
    for (int t = 0; t < 4; ++t) {
        b1f[t] = b1[16*t + n];
        b3f[t] = b3[16*t + n];
        b4f[t] = b4[16*t + n];
    }
    const float b2f = b2[n];
    const float b5f = (n < 3) ? b5[n] : 0.0f;

    const f32x4 zero4 = {0.f, 0.f, 0.f, 0.f};

    const int waveRow0 = blockIdx.x * ROWS_PER_BLOCK + w * (TPW * 16);

    bf16x8 pfrag = ldrow8(pos, (size_t)(waveRow0 + n) * 32 + 8*q);

    for (int t = 0; t < TPW; ++t) {
        const int row0 = waveRow0 + t * 16;
        const int tn   = (t + 1 < TPW) ? t + 1 : t;
        bf16x8 pnext = ldrow8(pos, (size_t)(waveRow0 + tn*16 + n) * 32 + 8*q);

        // ---- L1: H = relu(X @ W1 + b1)  [16x64] ----
        f32x4 acc1[4];
        #pragma unroll
        for (int tt = 0; tt < 4; ++tt)
            acc1[tt] = __builtin_amdgcn_mfma_f32_16x16x32_bf16(pfrag, w1f[tt], zero4, 0, 0, 0);
        #pragma unroll
        for (int r = 0; r < 4; ++r) {      // base + {0,16,32,48} -> ds_write2_b32 pairs
            float* p = hb + (4*q + r) * HS + n;
            p[0]  = fmaxf(acc1[0][r] + b1f[0], 0.f);
            p[16] = fmaxf(acc1[1][r] + b1f[1], 0.f);
            p[32] = fmaxf(acc1[2][r] + b1f[2], 0.f);
            p[48] = fmaxf(acc1[3][r] + b1f[3], 0.f);
        }
        FENCE();
        bf16x8 a2[2];
        #pragma unroll
        for (int kt = 0; kt < 2; ++kt) {   // 8 consecutive f32 -> 2x ds_read_b128
            const f32x4* pr = (const f32x4*)(hb + n * HS + 32*kt + 8*q);
            f32x4 u0 = pr[0], u1 = pr[1];
            #pragma unroll
            for (int j = 0; j < 4; ++j) { a2[kt][j] = (bf16_t)u0[j]; a2[kt][4+j] = (bf16_t)u1[j]; }
        }

        // ---- L2: density = H @ W2 + b2  [16x16] (no relu) ----
        f32x4 acc2 = __builtin_amdgcn_mfma_f32_16x16x32_bf16(a2[0], w2f[0], zero4, 0, 0, 0);
        acc2 = __builtin_amdgcn_mfma_f32_16x16x32_bf16(a2[1], w2f[1], acc2, 0, 0, 0);
        {
            float* p = cb + (4*q) * CS + n;    // base + {0,CS,2CS,3CS} -> write2 pairs
            p[0]    = acc2[0] + b2f;
            p[CS]   = acc2[1] + b2f;
            p[2*CS] = acc2[2] + b2f;
            p[3*CS] = acc2[3] + b2f;
        }
        FENCE();

        // ---- density store, fp32, coalesced f32x4 via LDS readback ----
        {
            const int rr = lane >> 2;            // 0..15
            const int cg = lane & 3;             // 4-col group
            f32x4 dv = *(const f32x4*)(cb + rr * CS + 4*cg);
            *(f32x4*)(outD + (size_t)(row0 + rr) * 16 + 4*cg) = dv;
        }

        // ---- a3: cols 0..15 from cb (q<2), cols 16..31 = SH computed in-register (q>=2) ----
        float av[8];
        {
            const f32x4* pr = (const f32x4*)(cb + n * CS + 8*(q & 1));
            f32x4 u0 = pr[0], u1 = pr[1];
            #pragma unroll
            for (int j = 0; j < 4; ++j) { av[j] = u0[j]; av[4+j] = u1[j]; }
        }
        if (q >= 2) {
            const size_t db = (size_t)(row0 + n) * 3;
            const float x = dir[db + 0], y = dir[db + 1], z = dir[db + 2];
            const float xx = x*x, yy = y*y, zz = z*z;
            if (q == 2) {   // SH comps 0..7
                av[0] = 0.28209479177387814f;
                av[1] = 0.4886025119029199f * y;
                av[2] = 0.4886025119029199f * z;
                av[3] = 0.4886025119029199f * x;
                av[4] = 1.0925484305920792f * x * y;
                av[5] = 1.0925484305920792f * y * z;
                av[6] = 0.9461746957575601f * zz - 0.31539156525252f;
                av[7] = 1.0925484305920792f * x * z;
            } else {        // SH comps 8..15
                av[0] = 0.5462742152960396f * (xx - yy);
                av[1] = 0.5900435899266435f * y * (3.f*xx - yy);
                av[2] = 2.890611442640554f * x * y * z;
                av[3] = 0.4570457994644658f * y * (5.f*zz - 1.f);
                av[4] = 0.3731763325901154f * z * (5.f*zz - 3.f);
                av[5] = 0.4570457994644658f * x * (5.f*zz - 1.f);
                av[6] = 1.445305721320277f  * z * (xx - yy);
                av[7] = 0.5900435899266435f * x * (xx - 3.f*yy);
            }
        }
        bf16x8 a3;
        #pragma unroll
        for (int j = 0; j < 8; ++j) a3[j] = (bf16_t)av[j];

        // ---- L3: relu(concat @ W3 + b3)  [16x64] ----
        f32x4 acc3[4];
        #pragma unroll
        for (int tt = 0; tt < 4; ++tt)
            acc3[tt] = __builtin_amdgcn_mfma_f32_16x16x32_bf16(a3, w3f[tt], zero4, 0, 0, 0);
        FENCE();   // a2 reads of hb are earlier in program order; safe to overwrite
        #pragma unroll
        for (int r = 0; r < 4; ++r) {
            float* p = hb + (4*q + r) * HS + n;
            p[0]  = fmaxf(acc3[0][r] + b3f[0], 0.f);
            p[16] = fmaxf(acc3[1][r] + b3f[1], 0.f);
            p[32] = fmaxf(acc3[2][r] + b3f[2], 0.f);
            p[48] = fmaxf(acc3[3][r] + b3f[3], 0.f);
        }
        FENCE();
        bf16x8 a4[2];
        #pragma unroll
        for (int kt = 0; kt < 2; ++kt) {
            const f32x4* pr = (const f32x4*)(hb + n * HS + 32*kt + 8*q);
            f32x4 u0 = pr[0], u1 = pr[1];
            #pragma unroll
            for (int j = 0; j < 4; ++j) { a4[kt][j] = (bf16_t)u0[j]; a4[kt][4+j] = (bf16_t)u1[j]; }
        }

        // ---- L4: relu(H3 @ W4 + b4)  [16x64] ----
        f32x4 acc4[4];
        #pragma unroll
        for (int tt = 0; tt < 4; ++tt) {
            acc4[tt] = __builtin_amdgcn_mfma_f32_16x16x32_bf16(a4[0], w4f[0][tt], zero4, 0, 0, 0);
            acc4[tt] = __builtin_amdgcn_mfma_f32_16x16x32_bf16(a4[1], w4f[1][tt], acc4[tt], 0, 0, 0);
        }
        FENCE();
        #pragma unroll
        for (int r = 0; r < 4; ++r) {
            float* p = hb + (4*q + r) * HS + n;
            p[0]  = fmaxf(acc4[0][r] + b4f[0], 0.f);
            p[16] = fmaxf(acc4[1][r] + b4f[1], 0.f);
            p[32] = fmaxf(acc4[2][r] + b4f[2], 0.f);
            p[48] = fmaxf(acc4[3][r] + b4f[3], 0.f);
        }
        FENCE();
        bf16x8 a5[2];
        #pragma unroll
        for (int kt = 0; kt < 2; ++kt) {
            const f32x4* pr = (const f32x4*)(hb + n * HS + 32*kt + 8*q);
            f32x4 u0 = pr[0], u1 = pr[1];
            #pragma unroll
            for (int j = 0; j < 4; ++j) { a5[kt][j] = (bf16_t)u0[j]; a5[kt][4+j] = (bf16_t)u1[j]; }
        }

        // ---- L5: color = sigmoid(H4 @ W5 + b5)  [16x3] ----
        f32x4 acc5 = __builtin_amdgcn_mfma_f32_16x16x32_bf16(a5[0], w5f[0], zero4, 0, 0, 0);
        acc5 = __builtin_amdgcn_mfma_f32_16x16x32_bf16(a5[1], w5f[1], acc5, 0, 0, 0);
        if (n < 3) {
            float* p = cb + (4*q) * CS + 32 + n;   // stage color in cb cols 32..34
            #pragma unroll
            for (int r = 0; r < 4; ++r) {
                float v = acc5[r] + b5f;
                p[r*CS] = 1.f / (1.f + __expf(-v));
            }
        }
        FENCE();
        if (lane < 48) {     // coalesced color store: lane = s*3 + c
            const int s = lane / 3, c = lane - 3*s;
            outC[(size_t)(row0 + s) * 3 + c] = cb[s * CS + 32 + c];
        }
        FENCE();   // WAR guard before next iteration overwrites hb/cb

        pfrag = pnext;
    }
}

extern "C" void kernel_launch(void* const* d_in, const int* in_sizes, int n_in,
                              void* d_out, int out_size, void* d_ws, size_t ws_size,
                              hipStream_t stream) {
    const float* pos = (const float*)d_in[0];
    const float* dir = (const float*)d_in[1];
    const float* W1  = (const float*)d_in[2];
    const float* b1  = (const float*)d_in[3];
    const float* W2  = (const float*)d_in[4];
    const float* b2  = (const float*)d_in[5];
    const float* W3  = (const float*)d_in[6];
    const float* b3  = (const float*)d_in[7];
    const float* W4  = (const float*)d_in[8];
    const float* b4  = (const float*)d_in[9];
    const float* W5  = (const float*)d_in[10];
    const float* b5  = (const float*)d_in[11];

    const int N = in_sizes[0] / 32;           // 1<<20
    float* outD = (float*)d_out;              // [N,16]
    float* outC = outD + (size_t)N * 16;      // [N,3]

    const int grid = N / ROWS_PER_BLOCK;      // 2048
    nerf_fused<<<grid, WAVES * 64, 0, stream>>>(pos, dir, W1, b1, W2, b2, W3, b3,
                                                W4, b4, W5, b5, outD, outC);
}

// Round 5
// 277.441 us; speedup vs baseline: 1.0359x; 1.0224x over previous
//
#include <hip/hip_runtime.h>
#include <hip/hip_bf16.h>

typedef __bf16 bf16_t;
typedef short  s4    __attribute__((ext_vector_type(4)));
typedef float  f32x4 __attribute__((ext_vector_type(4)));

#define TPW   8                      // 16-sample tiles per wave
#define WAVES 4
#define ROWS_PER_BLOCK (WAVES * TPW * 16)   // 512
#define CS 36                        // staging row stride (f32)

// compiler-ordering fence for wave-synchronous LDS staging (DS pipe is
// in-order within a wave; buffers are per-wave, no cross-wave sharing).
#define FENCE() __asm__ volatile("" ::: "memory")

__device__ __forceinline__ short bfs(float f) {
    return __builtin_bit_cast(short, (bf16_t)f);
}
__device__ __forceinline__ s4 pack4(f32x4 a) {
    s4 r; r[0]=bfs(a[0]); r[1]=bfs(a[1]); r[2]=bfs(a[2]); r[3]=bfs(a[3]); return r;
}
__device__ __forceinline__ s4 relu_pack4(f32x4 a) {
    s4 r;
    r[0]=bfs(fmaxf(a[0],0.f)); r[1]=bfs(fmaxf(a[1],0.f));
    r[2]=bfs(fmaxf(a[2],0.f)); r[3]=bfs(fmaxf(a[3],0.f));
    return r;
}
// D = A*B + C, 16x16x16 bf16. Layout identity used throughout:
// A[m=n][k=4q+i] (reg i) ; B[k=4q+i][c=n] (reg i) ; D[row=4q+r][c=n] (reg r)
// => a layer's D regs are exactly the next layer's B regs (same lane, same reg).
#define MFMA16(a,b,c) __builtin_amdgcn_mfma_f32_16x16x16bf16_1k(a, b, c, 0, 0, 0)

__global__ __launch_bounds__(256) void nerf_fused(
    const float* __restrict__ pos, const float* __restrict__ dir,
    const float* __restrict__ W1, const float* __restrict__ b1,
    const float* __restrict__ W2, const float* __restrict__ b2,
    const float* __restrict__ W3, const float* __restrict__ b3,
    const float* __restrict__ W4, const float* __restrict__ b4,
    const float* __restrict__ W5, const float* __restrict__ b5,
    float* __restrict__ outD, float* __restrict__ outC)
{
    __shared__ float cbuf[WAVES][16 * CS];

    const int tid  = threadIdx.x;
    const int w    = tid >> 6;
    const int lane = tid & 63;
    const int q    = lane >> 4;    // quad 0..3
    const int n    = lane & 15;    // A row / B col / sample-within-tile

    float* cb = cbuf[w];

    // ---------- weight A-fragments: wa[tile][ktile][i] = W^T[16t+n][16kt+4q+i] ----------
    s4 wa1[4][2], wa2[4], wa3[4][2], wa4[4][4], wa5[4];
    #pragma unroll
    for (int t = 0; t < 4; ++t)
        #pragma unroll
        for (int kt = 0; kt < 2; ++kt)
            #pragma unroll
            for (int i = 0; i < 4; ++i)
                wa1[t][kt][i] = bfs(W1[(16*kt + 4*q + i) * 64 + 16*t + n]);   // [32,64]
    #pragma unroll
    for (int kt = 0; kt < 4; ++kt)
        #pragma unroll
        for (int i = 0; i < 4; ++i)
            wa2[kt][i] = bfs(W2[(16*kt + 4*q + i) * 16 + n]);                 // [64,16]
    #pragma unroll
    for (int t = 0; t < 4; ++t)
        #pragma unroll
        for (int kt = 0; kt < 2; ++kt)
            #pragma unroll
            for (int i = 0; i < 4; ++i)
                wa3[t][kt][i] = bfs(W3[(16*kt + 4*q + i) * 64 + 16*t + n]);   // [32,64]
    #pragma unroll
    for (int t = 0; t < 4; ++t)
        #pragma unroll
        for (int kt = 0; kt < 4; ++kt)
            #pragma unroll
            for (int i = 0; i < 4; ++i)
                wa4[t][kt][i] = bfs(W4[(16*kt + 4*q + i) * 64 + 16*t + n]);   // [64,64]
    #pragma unroll
    for (int kt = 0; kt < 4; ++kt)
        #pragma unroll
        for (int i = 0; i < 4; ++i)
            wa5[kt][i] = (n < 3) ? bfs(W5[(16*kt + 4*q + i) * 3 + n]) : (short)0; // [64,3] pad

    // ---------- bias C-initializers (channel index = 4q+r within tile t) ----------
    f32x4 bi1[4], bi3[4], bi4[4], bi2, bi5;
    #pragma unroll
    for (int t = 0; t < 4; ++t)
        #pragma unroll
        for (int r = 0; r < 4; ++r) {
            bi1[t][r] = b1[16*t + 4*q + r];
            bi3[t][r] = b3[16*t + 4*q + r];
            bi4[t][r] = b4[16*t + 4*q + r];
        }
    #pragma unroll
    for (int r = 0; r < 4; ++r) {
        bi2[r] = b2[4*q + r];
        bi5[r] = (q == 0 && r < 3) ? b5[r] : 0.f;
    }

    const int waveRow0 = blockIdx.x * ROWS_PER_BLOCK + w * (TPW * 16);

    // prefetched raw inputs for tile 0
    f32x4 pa = *(const f32x4*)(pos + (size_t)(waveRow0 + n) * 32 + 4*q);
    f32x4 pb = *(const f32x4*)(pos + (size_t)(waveRow0 + n) * 32 + 16 + 4*q);
    float dx = dir[(size_t)(waveRow0 + n) * 3 + 0];
    float dy = dir[(size_t)(waveRow0 + n) * 3 + 1];
    float dz = dir[(size_t)(waveRow0 + n) * 3 + 2];

    for (int t = 0; t < TPW; ++t) {
        const int row0 = waveRow0 + t * 16;
        const int rn   = waveRow0 + ((t + 1 < TPW) ? t + 1 : t) * 16;
        f32x4 pa2 = *(const f32x4*)(pos + (size_t)(rn + n) * 32 + 4*q);
        f32x4 pb2 = *(const f32x4*)(pos + (size_t)(rn + n) * 32 + 16 + 4*q);
        float dx2 = dir[(size_t)(rn + n) * 3 + 0];
        float dy2 = dir[(size_t)(rn + n) * 3 + 1];
        float dz2 = dir[(size_t)(rn + n) * 3 + 2];

        // B-frags of X^T: B[k=16kt+4q+i][s=n] = pos[row0+n][16kt+4q+i]
        s4 xb0 = pack4(pa), xb1 = pack4(pb);

        // ---- L1: H^T = W1^T · X^T  (4 h-tiles, K=32) ----
        s4 hf[4];
        #pragma unroll
        for (int tt = 0; tt < 4; ++tt) {
            f32x4 h = MFMA16(wa1[tt][0], xb0, bi1[tt]);
            h = MFMA16(wa1[tt][1], xb1, h);
            hf[tt] = relu_pack4(h);          // D regs == next-layer B regs
        }

        // ---- L2: density^T = W2^T · H^T  (K=64, no relu) ----
        f32x4 d2 = bi2;
        #pragma unroll
        for (int kt = 0; kt < 4; ++kt)
            d2 = MFMA16(wa2[kt], hf[kt], d2);   // lane(q,n) reg r = density[s=n][c=4q+r]

        // stage density -> coalesced fp32 store
        *(f32x4*)(cb + n * CS + 4*q) = d2;
        FENCE();
        {
            const int rr = lane >> 2;            // sample 0..15
            const int cg = lane & 3;             // 4-channel group
            f32x4 dv = *(const f32x4*)(cb + rr * CS + 4*cg);
            *(f32x4*)(outD + (size_t)(row0 + rr) * 16 + 4*cg) = dv;
        }

        // ---- L3 B-operand: kt=0 raw density (same regs), kt=1 SH in-register ----
        s4 cf0 = pack4(d2);
        f32x4 shv;
        {
            const float xx = dx*dx, yy = dy*dy, zz = dz*dz;
            if (q == 0) {
                shv[0] = 0.28209479177387814f;
                shv[1] = 0.4886025119029199f * dy;
                shv[2] = 0.4886025119029199f * dz;
                shv[3] = 0.4886025119029199f * dx;
            } else if (q == 1) {
                shv[0] = 1.0925484305920792f * dx * dy;
                shv[1] = 1.0925484305920792f * dy * dz;
                shv[2] = 0.9461746957575601f * zz - 0.31539156525252f;
                shv[3] = 1.0925484305920792f * dx * dz;
            } else if (q == 2) {
                shv[0] = 0.5462742152960396f * (xx - yy);
                shv[1] = 0.5900435899266435f * dy * (3.f*xx - yy);
                shv[2] = 2.890611442640554f * dx * dy * dz;
                shv[3] = 0.4570457994644658f * dy * (5.f*zz - 1.f);
            } else {
                shv[0] = 0.3731763325901154f * dz * (5.f*zz - 3.f);
                shv[1] = 0.4570457994644658f * dx * (5.f*zz - 1.f);
                shv[2] = 1.445305721320277f  * dz * (xx - yy);
                shv[3] = 0.5900435899266435f * dx * (xx - 3.f*yy);
            }
        }
        s4 cf1 = pack4(shv);

        // ---- L3: relu(W3^T · concat^T)  (4 h-tiles, K=32) ----
        s4 gf[4];
        #pragma unroll
        for (int tt = 0; tt < 4; ++tt) {
            f32x4 g = MFMA16(wa3[tt][0], cf0, bi3[tt]);
            g = MFMA16(wa3[tt][1], cf1, g);
            gf[tt] = relu_pack4(g);
        }

        // ---- L4: relu(W4^T · H3^T)  (4 h-tiles, K=64) ----
        s4 ef[4];
        #pragma unroll
        for (int tt = 0; tt < 4; ++tt) {
            f32x4 e = bi4[tt];
            #pragma unroll
            for (int kt = 0; kt < 4; ++kt)
                e = MFMA16(wa4[tt][kt], gf[kt], e);
            ef[tt] = relu_pack4(e);
        }

        // ---- L5: color^T = W5^T · H4^T  (K=64) + sigmoid ----
        f32x4 c5 = bi5;
        #pragma unroll
        for (int kt = 0; kt < 4; ++kt)
            c5 = MFMA16(wa5[kt], ef[kt], c5);   // valid only q==0, r<3: color[s=n][c=r]
        if (q == 0) {
            f32x4 cv;
            cv[0] = 1.f / (1.f + __expf(-c5[0]));
            cv[1] = 1.f / (1.f + __expf(-c5[1]));
            cv[2] = 1.f / (1.f + __expf(-c5[2]));
            cv[3] = 0.f;
            *(f32x4*)(cb + n * CS + 32) = cv;   // stage at cols 32..35
        }
        FENCE();
        if (lane < 48) {                         // coalesced color store
            const int s = lane / 3, c = lane - 3*s;
            outC[(size_t)(row0 + s) * 3 + c] = cb[s * CS + 32 + c];
        }
        FENCE();   // WAR guard: cb readbacks precede next iter's writes (in-order DS)

        pa = pa2; pb = pb2; dx = dx2; dy = dy2; dz = dz2;
    }
}

extern "C" void kernel_launch(void* const* d_in, const int* in_sizes, int n_in,
                              void* d_out, int out_size, void* d_ws, size_t ws_size,
                              hipStream_t stream) {
    const float* pos = (const float*)d_in[0];
    const float* dir = (const float*)d_in[1];
    const float* W1  = (const float*)d_in[2];
    const float* b1  = (const float*)d_in[3];
    const float* W2  = (const float*)d_in[4];
    const float* b2  = (const float*)d_in[5];
    const float* W3  = (const float*)d_in[6];
    const float* b3  = (const float*)d_in[7];
    const float* W4  = (const float*)d_in[8];
    const float* b4  = (const float*)d_in[9];
    const float* W5  = (const float*)d_in[10];
    const float* b5  = (const float*)d_in[11];

    const int N = in_sizes[0] / 32;           // 1<<20
    float* outD = (float*)d_out;              // [N,16]
    float* outC = outD + (size_t)N * 16;      // [N,3]

    const int grid = N / ROWS_PER_BLOCK;      // 2048
    nerf_fused<<<grid, WAVES * 64, 0, stream>>>(pos, dir, W1, b1, W2, b2, W3, b3,
                                                W4, b4, W5, b5, outD, outC);
}